// Round 1
// baseline (1662.819 us; speedup 1.0000x reference)
//
#include <hip/hip_runtime.h>
#include <hip/hip_bf16.h>

// TT layer: out[n,a,b,c,d] = relu( sum_{i,j,k,l,r,s,t}
//   x[n,i,j,k,l] G1[a,i,r] G2[b,j,r,s] G3[c,k,s,t] G4[d,l,t] + bias[a,b,c,d] )
//
// Pass A: stages 1-2 -> T2[n, a, kl, (b*4+s)]  (bf16, in d_ws)
// Pass B: stages 3-4 -> out (fp32)
//
// Flat strides (fp32 inputs):
//   x:  n*65536 + i*4096 + j*256 + k*16 + l
//   G1: a*64 + i*4 + r            (16,16,4)
//   G2: b*256 + j*16 + r*4 + s    (16,16,4,4)
//   G3: c*256 + k*16 + s*4 + t    (16,16,4,4)
//   G4: d*64 + l*4 + t            (16,16,4)

#define T2_PER_N 262144  // 16(a) * 256(kl) * 64(b*4+s)

__global__ __launch_bounds__(256, 2) void tt_passA(
    const float* __restrict__ x,
    const float* __restrict__ G1,
    const float* __restrict__ G2,
    __hip_bfloat16* __restrict__ T2,
    int n0)
{
  const int tid = threadIdx.x;
  const int klc = blockIdx.x;          // kl chunk of 8: kl = klc*8 + ll
  const int n   = n0 + (int)blockIdx.y;

  __shared__ float xs [16 * 132];      // col-major A1: [i][m1 = j*8+ll]
  __shared__ float g1s[16 * 64];       // [i][a*4+r]
  __shared__ float g2s[64 * 64];       // [j*4+r][b*4+s]
  __shared__ float t1s[64 * 132];      // col-major A2: [j*4+r][m2 = a*8+ll]

  for (int idx = tid; idx < 1024; idx += 256) {
    const int i = idx >> 6, a = (idx >> 2) & 15, r = idx & 3;
    g1s[idx] = G1[a * 64 + i * 4 + r];
  }
  for (int idx = tid; idx < 4096; idx += 256) {
    const int j = idx >> 8, r = (idx >> 6) & 3, b = (idx >> 2) & 15, s = idx & 3;
    g2s[idx] = G2[b * 256 + j * 16 + r * 4 + s];
  }
  {
    const float* xblk = x + (size_t)n * 65536 + klc * 8;
    #pragma unroll
    for (int it = 0; it < 2; ++it) {
      const int f = it * 256 + tid;                 // [0,512) float4s
      const int i = f >> 5, j = (f >> 1) & 15, lq = f & 1;
      const float4 v = *(const float4*)(xblk + i * 4096 + j * 256 + lq * 4);
      *(float4*)(&xs[i * 132 + j * 8 + lq * 4]) = v;
    }
  }
  __syncthreads();

  const int mg = tid >> 3, ng = tid & 7;  // thread tile: 4 rows x 8 cols

  // ---- stage 1: T1[j,ll,(a,r)] = sum_i x[i,(j,ll)] * G1m[i,(a,r)]
  //      M=128 (j*8+ll), N=64 (a*4+r), K=16 (i)
  {
    float acc[4][8];
    #pragma unroll
    for (int u = 0; u < 4; ++u)
      #pragma unroll
      for (int v = 0; v < 8; ++v) acc[u][v] = 0.f;
    #pragma unroll
    for (int i = 0; i < 16; ++i) {
      const float4 av = *(const float4*)(&xs[i * 132 + mg * 4]);
      const float4 b0 = *(const float4*)(&g1s[i * 64 + ng * 8]);
      const float4 b1 = *(const float4*)(&g1s[i * 64 + ng * 8 + 4]);
      const float am[4] = {av.x, av.y, av.z, av.w};
      const float bn[8] = {b0.x, b0.y, b0.z, b0.w, b1.x, b1.y, b1.z, b1.w};
      #pragma unroll
      for (int u = 0; u < 4; ++u)
        #pragma unroll
        for (int v = 0; v < 8; ++v) acc[u][v] += am[u] * bn[v];
    }
    // scatter to t1s col-major for stage 2: [k2=(j*4+r)][m2=(a*8+ll)]
    #pragma unroll
    for (int u = 0; u < 4; ++u) {
      const int m1 = mg * 4 + u, j = m1 >> 3, ll = m1 & 7;
      #pragma unroll
      for (int v = 0; v < 8; ++v) {
        const int n1 = ng * 8 + v, a = n1 >> 2, r = n1 & 3;
        t1s[(j * 4 + r) * 132 + a * 8 + ll] = acc[u][v];
      }
    }
  }
  __syncthreads();

  // ---- stage 2: T2[(a,ll),(b,s)] = sum_{j,r} T1 * G2m
  //      M=128 (a*8+ll), N=64 (b*4+s), K=64 (j*4+r)
  {
    float acc[4][8];
    #pragma unroll
    for (int u = 0; u < 4; ++u)
      #pragma unroll
      for (int v = 0; v < 8; ++v) acc[u][v] = 0.f;
    #pragma unroll 4
    for (int k = 0; k < 64; ++k) {
      const float4 av = *(const float4*)(&t1s[k * 132 + mg * 4]);
      const float4 b0 = *(const float4*)(&g2s[k * 64 + ng * 8]);
      const float4 b1 = *(const float4*)(&g2s[k * 64 + ng * 8 + 4]);
      const float am[4] = {av.x, av.y, av.z, av.w};
      const float bn[8] = {b0.x, b0.y, b0.z, b0.w, b1.x, b1.y, b1.z, b1.w};
      #pragma unroll
      for (int u = 0; u < 4; ++u)
        #pragma unroll
        for (int v = 0; v < 8; ++v) acc[u][v] += am[u] * bn[v];
    }
    // store T2[n'][a][kl][b*4+s] as bf16, 8 consecutive per row -> uint4
    __hip_bfloat16* tb = T2 + (size_t)blockIdx.y * T2_PER_N;
    #pragma unroll
    for (int u = 0; u < 4; ++u) {
      const int m2 = mg * 4 + u, a = m2 >> 3, ll = m2 & 7;
      union { __hip_bfloat16 h[8]; uint4 q; } pk;
      #pragma unroll
      for (int v = 0; v < 8; ++v) pk.h[v] = __float2bfloat16(acc[u][v]);
      *(uint4*)(tb + a * 16384 + (klc * 8 + ll) * 64 + ng * 8) = pk.q;
    }
  }
}

__global__ __launch_bounds__(256, 2) void tt_passB(
    const __hip_bfloat16* __restrict__ T2,
    const float* __restrict__ G3,
    const float* __restrict__ G4,
    const float* __restrict__ bias,
    float* __restrict__ out,
    int n0)
{
  const int tid = threadIdx.x;
  const int a   = blockIdx.x >> 1;
  const int bh  = blockIdx.x & 1;       // b half: b = bh*8 + bp
  const int n   = n0 + (int)blockIdx.y;

  __shared__ float g3s[64 * 64];        // [k*4+s][c*4+t]
  __shared__ float g4s[64 * 16];        // [t*16+l][d]
  __shared__ float t23[64 * 132];       // stage3 A: [k*4+s][bp*16+l]; then stage4 A: [t*16+l][bp*16+c]

  for (int idx = tid; idx < 4096; idx += 256) {
    const int k = idx >> 8, s = (idx >> 6) & 3, c = (idx >> 2) & 15, t = idx & 3;
    g3s[idx] = G3[c * 256 + k * 16 + s * 4 + t];
  }
  for (int idx = tid; idx < 1024; idx += 256) {
    const int t = idx >> 8, l = (idx >> 4) & 15, d = idx & 15;
    g4s[idx] = G4[d * 64 + l * 4 + t];
  }
  {
    const __hip_bfloat16* tb =
        T2 + (size_t)blockIdx.y * T2_PER_N + a * 16384 + bh * 32;
    #pragma unroll
    for (int it = 0; it < 4; ++it) {
      const int e8  = it * 256 + tid;   // [0,1024) groups of 8 bf16
      const int kl  = e8 >> 2;
      const int rem = (e8 & 3) * 8;     // offset within 32-wide half row
      union { uint4 q; __hip_bfloat16 h[8]; } pk;
      pk.q = *(const uint4*)(tb + kl * 64 + rem);
      const int k = kl >> 4, l = kl & 15;
      #pragma unroll
      for (int qi = 0; qi < 8; ++qi) {
        const int bs = rem + qi, bp = bs >> 2, s = bs & 3;
        t23[(k * 4 + s) * 132 + bp * 16 + l] = __bfloat162float(pk.h[qi]);
      }
    }
  }
  __syncthreads();

  const int mg = tid >> 3, ng = tid & 7;

  // ---- stage 3: T3[(bp,l),(c,t)] = sum_{k,s} T2 * G3m
  //      M=128 (bp*16+l), N=64 (c*4+t), K=64 (k*4+s)
  float acc3[4][8];
  #pragma unroll
  for (int u = 0; u < 4; ++u)
    #pragma unroll
    for (int v = 0; v < 8; ++v) acc3[u][v] = 0.f;
  #pragma unroll 4
  for (int k = 0; k < 64; ++k) {
    const float4 av = *(const float4*)(&t23[k * 132 + mg * 4]);
    const float4 b0 = *(const float4*)(&g3s[k * 64 + ng * 8]);
    const float4 b1 = *(const float4*)(&g3s[k * 64 + ng * 8 + 4]);
    const float am[4] = {av.x, av.y, av.z, av.w};
    const float bn[8] = {b0.x, b0.y, b0.z, b0.w, b1.x, b1.y, b1.z, b1.w};
    #pragma unroll
    for (int u = 0; u < 4; ++u)
      #pragma unroll
      for (int v = 0; v < 8; ++v) acc3[u][v] += am[u] * bn[v];
  }
  __syncthreads();  // all stage-3 reads of t23 done before overwrite

  // scatter T3 col-major for stage 4: [k4=(t*16+l)][m4=(bp*16+c)]
  #pragma unroll
  for (int u = 0; u < 4; ++u) {
    const int m3 = mg * 4 + u, bp = m3 >> 4, l = m3 & 15;
    #pragma unroll
    for (int v = 0; v < 8; ++v) {
      const int n3 = ng * 8 + v, c = n3 >> 2, t = n3 & 3;
      t23[(t * 16 + l) * 132 + bp * 16 + c] = acc3[u][v];
    }
  }
  __syncthreads();

  // ---- stage 4: out[(bp,c),d] = sum_{t,l} T3 * G4m
  //      M=128 (bp*16+c), N=16 (d), K=64 (t*16+l); thread: 4 rows x 2 d
  float acc4[4][2];
  #pragma unroll
  for (int u = 0; u < 4; ++u) { acc4[u][0] = 0.f; acc4[u][1] = 0.f; }
  #pragma unroll 4
  for (int k = 0; k < 64; ++k) {
    const float4 av = *(const float4*)(&t23[k * 132 + mg * 4]);
    const float2 bv = *(const float2*)(&g4s[k * 16 + ng * 2]);
    const float am[4] = {av.x, av.y, av.z, av.w};
    #pragma unroll
    for (int u = 0; u < 4; ++u) {
      acc4[u][0] += am[u] * bv.x;
      acc4[u][1] += am[u] * bv.y;
    }
  }
  // epilogue: bias + relu, write out[n, a, b, c, d]
  #pragma unroll
  for (int u = 0; u < 4; ++u) {
    const int m4 = mg * 4 + u, bp = m4 >> 4, c = m4 & 15;
    const int b = bh * 8 + bp;
    const int off = a * 4096 + b * 256 + c * 16 + ng * 2;
    const float2 bv = *(const float2*)(bias + off);
    float2 o;
    o.x = fmaxf(acc4[u][0] + bv.x, 0.f);
    o.y = fmaxf(acc4[u][1] + bv.y, 0.f);
    *(float2*)(out + (size_t)n * 65536 + off) = o;
  }
}

extern "C" void kernel_launch(void* const* d_in, const int* in_sizes, int n_in,
                              void* d_out, int out_size, void* d_ws, size_t ws_size,
                              hipStream_t stream) {
  const float* x    = (const float*)d_in[0];
  const float* G1   = (const float*)d_in[1];
  const float* G2   = (const float*)d_in[2];
  const float* G3   = (const float*)d_in[3];
  const float* G4   = (const float*)d_in[4];
  const float* bias = (const float*)d_in[5];
  float* out = (float*)d_out;
  __hip_bfloat16* T2 = (__hip_bfloat16*)d_ws;

  const int B = 1024;
  const size_t per_n = (size_t)T2_PER_N * sizeof(__hip_bfloat16);  // 512 KB
  int chunk = (int)(ws_size / per_n);
  if (chunk > B) chunk = B;
  if (chunk < 1) chunk = 1;  // requires ws_size >= 512 KB

  for (int nn0 = 0; nn0 < B; nn0 += chunk) {
    const int c = (nn0 + chunk <= B) ? chunk : (B - nn0);
    tt_passA<<<dim3(32, c), 256, 0, stream>>>(x, G1, G2, T2, nn0);
    tt_passB<<<dim3(32, c), 256, 0, stream>>>(T2, G3, G4, bias, out, nn0);
  }
}

// Round 2
// 670.753 us; speedup vs baseline: 2.4790x; 2.4790x over previous
//
#include <hip/hip_runtime.h>
#include <hip/hip_bf16.h>

// TT layer via MFMA bf16:
// out[n,a,b,c,d] = relu( sum x[n,ijkl] G1[a,i,r] G2[b,j,r,s] G3[c,k,s,t] G4[d,l,t] + bias[abcd] )
//
// Pass A (block = n, k):  stage1: T1[(j,l),(a,r)] = x^T G1   (K=16 zero-padded to 32)
//                         stage2: T2[(a,l),(b,s)] = T1 G2    (K=64)
//                         -> T2 global [n'][a][k*16+l][b*4+s] bf16 (d_ws)
// Pass B (block = n, a):  stage3: T3[(b,l),(c,t)] = T2 G3    (K=64)
//                         stage4: out[(b,c),d]    = T3 G4    (K=64) + bias, relu
//
// MFMA 16x16x32 bf16 layouts (gfx950, HW-verified per guide):
//   A frag: lane holds A[m=ln][k=quad*8+j]  (8 bf16, ds_read_b128 from [m][k] rows)
//   B frag: lane holds B[k=quad*8+j][n=ln]  (same shape from [n][k] rows)
//   C/D:    col=ln, row=quad*4+reg
// Operand-swap trick: mfma(b_frag, a_frag) = C^T -> regs span the N index, so
// inter-stage repack is a packed ds_write_b64 instead of 4 scalar scatters.

typedef __attribute__((ext_vector_type(8))) short bf16x8;
typedef __attribute__((ext_vector_type(4))) float f32x4;
typedef unsigned short u16;
typedef unsigned long long u64;

#define T2_PER_N 262144           // 16(a) * 256(kl) * 64(b*4+s) bf16 elems
#define PAD40 40                  // 16 real K + 16 zeros + 8 pad (stage-1 rows)
#define PAD72 72                  // 64 K + 8 pad (144B rows, 16B aligned, 2-way)

static __device__ __forceinline__ u16 f2bf(float f) {
  __hip_bfloat16 h = __float2bfloat16(f);
  return *reinterpret_cast<u16*>(&h);
}
static __device__ __forceinline__ u64 pack4(f32x4 a) {
  union { u16 s[4]; u64 u; } p;
  p.s[0] = f2bf(a[0]); p.s[1] = f2bf(a[1]); p.s[2] = f2bf(a[2]); p.s[3] = f2bf(a[3]);
  return p.u;
}
#define MFMA(A, B, C) __builtin_amdgcn_mfma_f32_16x16x32_bf16((A), (B), (C), 0, 0, 0)

__global__ __launch_bounds__(256, 2) void tt_passA(
    const float* __restrict__ x, const float* __restrict__ G1,
    const float* __restrict__ G2, u16* __restrict__ T2, int n0)
{
  const int tid = threadIdx.x;
  const int k    = blockIdx.x;          // one k per block, all (i,j,l)
  const int slot = blockIdx.y;
  const int n = n0 + slot;
  const int lane = tid & 63, w = tid >> 6, quad = lane >> 4, ln = lane & 15;

  __shared__ __align__(16) u16 xs [256 * PAD40];  // A1: [m1=j*16+l][i 0..15, zeros 16..31]
  __shared__ __align__(16) u16 g1s[ 64 * PAD40];  // B1: [n1=a*4+r][i]
  __shared__ __align__(16) u16 t1s[256 * PAD72];  // A2: [m2=a*16+l][k2=j*4+r]; reused as T2 staging
  __shared__ __align__(16) u16 g2s[ 64 * PAD72];  // B2: [n2=b*4+s][k2]

  // ---- staging ----
  {  // zero the padded K half (cols 16..31) of xs and g1s
    const uint4 z = {0, 0, 0, 0};
    for (int idx = tid; idx < 640; idx += 256) {
      if (idx < 512) *(uint4*)&xs [(idx >> 1) * PAD40 + 16 + (idx & 1) * 8] = z;
      else           *(uint4*)&g1s[((idx - 512) >> 1) * PAD40 + 16 + (idx & 1) * 8] = z;
    }
  }
  #pragma unroll
  for (int it = 0; it < 4; ++it) {      // G1[a,i,r] -> g1s[a*4+r][i]
    const int e = it * 256 + tid, a = e >> 6, i = (e >> 2) & 15, r = e & 3;
    g1s[(a * 4 + r) * PAD40 + i] = f2bf(G1[e]);
  }
  #pragma unroll
  for (int it = 0; it < 16; ++it) {     // G2[b,j,r,s] -> g2s[b*4+s][j*4+r]
    const int e = it * 256 + tid, b = e >> 8, j = (e >> 4) & 15, r = (e >> 2) & 3, s = e & 3;
    g2s[(b * 4 + s) * PAD72 + j * 4 + r] = f2bf(G2[e]);
  }
  {  // x[i,j,k,l] -> xs[j*16+l][i]; i in bits 2..5 so scatter writes spread banks
    const float4* xg = (const float4*)x + (size_t)n * 16384;
    #pragma unroll
    for (int it = 0; it < 4; ++it) {
      const int e = it * 256 + tid, i = (e >> 2) & 15, j = e >> 6, lq = e & 3;
      const float4 v = xg[i * 1024 + j * 64 + k * 4 + lq];
      const float vv[4] = {v.x, v.y, v.z, v.w};
      #pragma unroll
      for (int u = 0; u < 4; ++u) xs[(j * 16 + lq * 4 + u) * PAD40 + i] = f2bf(vv[u]);
    }
  }
  __syncthreads();

  // ---- stage 1 (swapped: regs span n1=(a,r) so t1s write packs along k2=j*4+r) ----
  {
    bf16x8 a1[4];
    #pragma unroll
    for (int t = 0; t < 4; ++t)
      a1[t] = *(const bf16x8*)&xs[((w * 4 + t) * 16 + ln) * PAD40 + quad * 8];
    #pragma unroll
    for (int tn = 0; tn < 4; ++tn) {
      const bf16x8 b1 = *(const bf16x8*)&g1s[(tn * 16 + ln) * PAD40 + quad * 8];
      #pragma unroll
      for (int t = 0; t < 4; ++t) {
        f32x4 acc = {0.f, 0.f, 0.f, 0.f};
        acc = MFMA(b1, a1[t], acc);     // swapped: row=n1_local, col=m1_local
        // elem (j=w*4+t, l=ln, a=tn*4+quad, r=reg) -> t1s[a*16+l][j*4+r]
        *(u64*)&t1s[((tn * 4 + quad) * 16 + ln) * PAD72 + (w * 4 + t) * 4] = pack4(acc);
      }
    }
  }
  __syncthreads();

  // ---- stage 2 (swapped: regs span n2=(b,s) -> T2 staging rows pack along bs) ----
  {
    bf16x8 a2[4][2];
    #pragma unroll
    for (int t = 0; t < 4; ++t)
      #pragma unroll
      for (int ks = 0; ks < 2; ++ks)
        a2[t][ks] = *(const bf16x8*)&t1s[((w * 4 + t) * 16 + ln) * PAD72 + ks * 32 + quad * 8];
    __syncthreads();  // all t1s frag reads done before overlaying it as T2 staging
    #pragma unroll
    for (int tn = 0; tn < 4; ++tn) {
      const bf16x8 b20 = *(const bf16x8*)&g2s[(tn * 16 + ln) * PAD72 + quad * 8];
      const bf16x8 b21 = *(const bf16x8*)&g2s[(tn * 16 + ln) * PAD72 + 32 + quad * 8];
      #pragma unroll
      for (int t = 0; t < 4; ++t) {
        f32x4 acc = {0.f, 0.f, 0.f, 0.f};
        acc = MFMA(b20, a2[t][0], acc);
        acc = MFMA(b21, a2[t][1], acc);
        // elem (a=w*4+t, l=ln, bs=tn*16+quad*4+reg) -> staging row a*16+l (wave-private rows)
        *(u64*)&t1s[((w * 4 + t) * 16 + ln) * PAD72 + tn * 16 + quad * 4] = pack4(acc);
      }
    }
  }
  __syncthreads();

  // ---- coalesced store: staging row (a*16+l) of 64 bf16 -> T2[a][k*16+l][bs] ----
  {
    uint4* Tg = (uint4*)(T2 + (size_t)slot * T2_PER_N);
    #pragma unroll
    for (int it = 0; it < 8; ++it) {
      const int e = it * 256 + tid, row = e >> 3, seg = e & 7;
      const uint4 q = *(const uint4*)&t1s[row * PAD72 + seg * 8];
      Tg[(row >> 4) * 2048 + k * 128 + (row & 15) * 8 + seg] = q;
    }
  }
}

__global__ __launch_bounds__(256, 2) void tt_passB(
    const u16* __restrict__ T2, const float* __restrict__ G3,
    const float* __restrict__ G4, const float* __restrict__ bias,
    float* __restrict__ out, int n0)
{
  const int tid = threadIdx.x;
  const int a    = blockIdx.x;
  const int slot = blockIdx.y;
  const int n = n0 + slot;
  const int lane = tid & 63, w = tid >> 6, quad = lane >> 4, ln = lane & 15;

  __shared__ __align__(16) u16 t2a[256 * PAD72];  // A3: [m3=b*16+l][k3=k*4+s]; reused as A4
  __shared__ __align__(16) u16 g3s[ 64 * PAD72];  // B3: [n3=c*4+t][k3]
  __shared__ __align__(16) u16 g4s[ 16 * PAD72];  // B4: [d][k4=t*16+l]

  // ---- staging ----
  #pragma unroll
  for (int it = 0; it < 16; ++it) {     // G3[c,k,s,t] -> g3s[c*4+t][k*4+s]
    const int e = it * 256 + tid, c = e >> 8, k = (e >> 4) & 15, s = (e >> 2) & 3, t = e & 3;
    g3s[(c * 4 + t) * PAD72 + k * 4 + s] = f2bf(G3[e]);
  }
  #pragma unroll
  for (int it = 0; it < 4; ++it) {      // G4[d,l,t] -> g4s[d][t*16+l]
    const int e = it * 256 + tid, d = e >> 6, l = (e >> 2) & 15, t = e & 3;
    g4s[d * PAD72 + t * 16 + l] = f2bf(G4[e]);
  }
  {  // T2[a][k*16+l][bs] (coalesced uint4) -> t2a[b*16+l][k*4+s] (b64 per 4-s group)
    const uint4* Tg = (const uint4*)(T2 + (size_t)slot * T2_PER_N) + a * 2048;
    #pragma unroll
    for (int it = 0; it < 8; ++it) {
      const int e = it * 256 + tid, kl = e >> 3, bq = e & 7;
      const uint4 q = Tg[e];
      const int k = kl >> 4, l = kl & 15, b0 = bq * 2;
      const u64 lo = ((u64)q.y << 32) | q.x, hi = ((u64)q.w << 32) | q.z;
      *(u64*)&t2a[(b0 * 16 + l) * PAD72 + k * 4]      = lo;  // b = b0,   s = 0..3
      *(u64*)&t2a[(b0 * 16 + l + 16) * PAD72 + k * 4] = hi;  // b = b0+1
    }
  }
  __syncthreads();

  // ---- stage 3 (normal: regs span m3 -> l, so t3s write packs along k4=t*16+l) ----
  {
    bf16x8 a3[4][2];
    #pragma unroll
    for (int t = 0; t < 4; ++t)
      #pragma unroll
      for (int ks = 0; ks < 2; ++ks)
        a3[t][ks] = *(const bf16x8*)&t2a[((w * 4 + t) * 16 + ln) * PAD72 + ks * 32 + quad * 8];
    __syncthreads();  // all t2a frag reads done before overlay as t3s
    #pragma unroll
    for (int tn = 0; tn < 4; ++tn) {
      const bf16x8 b30 = *(const bf16x8*)&g3s[(tn * 16 + ln) * PAD72 + quad * 8];
      const bf16x8 b31 = *(const bf16x8*)&g3s[(tn * 16 + ln) * PAD72 + 32 + quad * 8];
      #pragma unroll
      for (int t = 0; t < 4; ++t) {
        f32x4 acc = {0.f, 0.f, 0.f, 0.f};
        acc = MFMA(a3[t][0], b30, acc);  // normal: row=m3_local, col=n3_local
        acc = MFMA(a3[t][1], b31, acc);
        // elem (b=w*4+t, l=quad*4+reg, c=tn*4+(ln>>2), t3=ln&3) -> t3s[b*16+c][t3*16+l]
        *(u64*)&t2a[((w * 4 + t) * 16 + tn * 4 + (ln >> 2)) * PAD72 + (ln & 3) * 16 + quad * 4]
            = pack4(acc);
      }
    }
  }
  __syncthreads();

  // ---- stage 4 + epilogue ----
  {
    bf16x8 b4[2];
    #pragma unroll
    for (int ks = 0; ks < 2; ++ks)
      b4[ks] = *(const bf16x8*)&g4s[ln * PAD72 + ks * 32 + quad * 8];
    const size_t obase = (size_t)n * 65536;
    #pragma unroll
    for (int t = 0; t < 4; ++t) {
      bf16x8 a40 = *(const bf16x8*)&t2a[((w * 4 + t) * 16 + ln) * PAD72 + quad * 8];
      bf16x8 a41 = *(const bf16x8*)&t2a[((w * 4 + t) * 16 + ln) * PAD72 + 32 + quad * 8];
      f32x4 acc = {0.f, 0.f, 0.f, 0.f};
      acc = MFMA(a40, b4[0], acc);
      acc = MFMA(a41, b4[1], acc);
      #pragma unroll
      for (int r = 0; r < 4; ++r) {
        const int m4 = (w * 4 + t) * 16 + quad * 4 + r;      // b*16+c
        const int off = a * 4096 + m4 * 16 + ln;             // within-sample offset
        const float v = acc[r] + bias[off];
        out[obase + off] = fmaxf(v, 0.f);
      }
    }
  }
}

extern "C" void kernel_launch(void* const* d_in, const int* in_sizes, int n_in,
                              void* d_out, int out_size, void* d_ws, size_t ws_size,
                              hipStream_t stream) {
  const float* x    = (const float*)d_in[0];
  const float* G1   = (const float*)d_in[1];
  const float* G2   = (const float*)d_in[2];
  const float* G3   = (const float*)d_in[3];
  const float* G4   = (const float*)d_in[4];
  const float* bias = (const float*)d_in[5];
  float* out = (float*)d_out;
  u16* T2 = (u16*)d_ws;

  const int B = 1024;
  const size_t per_n = (size_t)T2_PER_N * sizeof(u16);  // 512 KB
  int chunk = (int)(ws_size / per_n);
  if (chunk > B) chunk = B;
  if (chunk < 1) chunk = 1;

  for (int nn0 = 0; nn0 < B; nn0 += chunk) {
    const int c = (nn0 + chunk <= B) ? chunk : (B - nn0);
    tt_passA<<<dim3(16, c), 256, 0, stream>>>(x, G1, G2, T2, nn0);
    tt_passB<<<dim3(16, c), 256, 0, stream>>>(T2, G3, G4, bias, out, nn0);
  }
}